// Round 1
// baseline (80.103 us; speedup 1.0000x reference)
//
#include <hip/hip_runtime.h>
#include <hip/hip_bf16.h>
#include <stdint.h>

// out[b,j] = sum_{i,k} softmax(alphas[i,j,:])[k] * coeffs[i,j,k] * prim_k(x[b,i])
// == P @ W2, P[b, i*8+k] = prim_k(x[b,i]) (prim_0 == 0), W2[i*8+k][j].
// M=65536, Kdim=512, N=64. bf16 MFMA 16x16x32.
//
// A-fragment (m=lane&15, k=quad*8+j): lane's 8 A elems = 8 prims of x[b, c*4+quad]
//   -> prims computed in registers, never staged.
// B-fragment (n=lane&15, k=quad*8+j): W2 pre-swizzled by build_w into
//   flat pos ((c*4+t)*64 + lane)*8 + j so main kernel ds_read_b128's directly.
// C/D layout: col=lane&15, row=quad*4+reg (m89-verified).

typedef __bf16 bf16x8 __attribute__((ext_vector_type(8)));
typedef float f32x4 __attribute__((ext_vector_type(4)));

typedef __attribute__((address_space(1))) void gvoid;
typedef __attribute__((address_space(3))) void lvoid;

__device__ __forceinline__ void async16(const void* g, void* l) {
    // global -> LDS direct copy, 16 B/lane; LDS dest = wave-uniform base + lane*16
    __builtin_amdgcn_global_load_lds((gvoid*)g, (lvoid*)l, 16, 0, 0);
}

// ---------------- kernel 1: build W2 in MFMA B-fragment order (bf16) --------
__global__ void build_w(const float* __restrict__ alphas,
                        const float* __restrict__ coeffs,
                        __bf16* __restrict__ w2) {
    int gid = blockIdx.x * blockDim.x + threadIdx.x;   // 0..4095 == i*64 + n
    int i = gid >> 6;
    int n = gid & 63;
    const float* a = alphas + gid * 8;
    const float* c = coeffs + gid * 8;

    float av[8], mx = -1e30f;
#pragma unroll
    for (int k = 0; k < 8; ++k) { av[k] = a[k]; mx = fmaxf(mx, av[k]); }
    float e[8], s = 0.f;
#pragma unroll
    for (int k = 0; k < 8; ++k) { e[k] = __expf(av[k] - mx); s += e[k]; }
    float inv = 1.0f / s;

    bf16x8 w;
#pragma unroll
    for (int k = 0; k < 8; ++k) w[k] = (__bf16)(e[k] * inv * c[k]);

    // k_global = i*8+op -> chunk cc=i>>2, quad q=i&3, j=op; n -> tile t=n>>4, nl=n&15
    int cc = i >> 2, q = i & 3, t = n >> 4, nl = n & 15;
    int pos = ((cc * 4 + t) * 64 + q * 16 + nl) * 8;
    *(bf16x8*)(w2 + pos) = w;    // 16B store, coalesced across nl
}

// ---------------- kernel 2: main GEMM -------------------------------------
// grid 512 x 256 threads (4 waves). LDS: W2 64KB + x-tile 16KB = 80KB (2 blk/CU).
// Each block: 2 tiles of 64 rows; each wave: 16 rows x 64 cols.
__global__ __launch_bounds__(256) void darts_main(const float* __restrict__ x,
                                                  const __bf16* __restrict__ w2,
                                                  float* __restrict__ out) {
    __shared__ __bf16 wlds[32768];   // 64 KB, B-fragment order
    __shared__ float  xs[4096];      // 16 KB, 64 rows x 64 cols

    const int tid  = threadIdx.x;
    const int lane = tid & 63;
    const int wv   = tid >> 6;

    // stage W2: straight 64KB copy (16 iters x 256 threads x 16B)
#pragma unroll
    for (int it = 0; it < 16; ++it) {
        async16((const char*)w2 + (it * 256 + tid) * 16,
                (char*)wlds + it * 4096 + wv * 1024);
    }

    const int m  = lane & 15;    // A row within 16-tile
    const int q  = lane >> 4;    // quad

    for (int tile = blockIdx.x; tile < 1024; tile += gridDim.x) {
        // stage x-tile: 64 rows x 64 cols fp32 = 16KB (4 iters x 256 x 16B)
#pragma unroll
        for (int it = 0; it < 4; ++it) {
            async16((const char*)x + tile * 16384 + (it * 256 + tid) * 16,
                    (char*)xs + it * 4096 + wv * 1024);
        }
        __syncthreads();   // drains vmcnt(0): W2 + x-tile resident

        f32x4 acc0 = {0.f, 0.f, 0.f, 0.f};
        f32x4 acc1 = {0.f, 0.f, 0.f, 0.f};
        f32x4 acc2 = {0.f, 0.f, 0.f, 0.f};
        f32x4 acc3 = {0.f, 0.f, 0.f, 0.f};

        const float* xrow = xs + (wv * 16 + m) * 64;

#pragma unroll
        for (int c = 0; c < 16; ++c) {
            float xv = xrow[c * 4 + q];          // 16-way same-addr broadcast: free
            float x2 = xv * xv;
            bf16x8 a;
            a[0] = (__bf16)0.0f;                 // 'none'
            a[1] = (__bf16)xv;                   // linear
            a[2] = (__bf16)x2;                   // x^2
            a[3] = (__bf16)(x2 * xv);            // x^3
            a[4] = (__bf16)__expf(xv);           // exp
            a[5] = (__bf16)__logf(xv);           // ln
            a[6] = (__bf16)__builtin_amdgcn_rcpf(xv); // 1/x
            a[7] = (__bf16)__sinf(xv);           // sin

            const __bf16* bbase = wlds + (c * 4) * 512 + lane * 8;
            bf16x8 b0 = *(const bf16x8*)(bbase);
            bf16x8 b1 = *(const bf16x8*)(bbase + 512);
            bf16x8 b2 = *(const bf16x8*)(bbase + 1024);
            bf16x8 b3 = *(const bf16x8*)(bbase + 1536);
            acc0 = __builtin_amdgcn_mfma_f32_16x16x32_bf16(a, b0, acc0, 0, 0, 0);
            acc1 = __builtin_amdgcn_mfma_f32_16x16x32_bf16(a, b1, acc1, 0, 0, 0);
            acc2 = __builtin_amdgcn_mfma_f32_16x16x32_bf16(a, b2, acc2, 0, 0, 0);
            acc3 = __builtin_amdgcn_mfma_f32_16x16x32_bf16(a, b3, acc3, 0, 0, 0);
        }

        __syncthreads();   // all waves done reading xs before next tile's DMA

        // epilogue: C layout col=lane&15, row=q*4+r
        float* orow = out + (tile * 64 + wv * 16 + q * 4) * 64 + m;
#pragma unroll
        for (int r = 0; r < 4; ++r) {
            orow[r * 64 + 0]  = acc0[r];
            orow[r * 64 + 16] = acc1[r];
            orow[r * 64 + 32] = acc2[r];
            orow[r * 64 + 48] = acc3[r];
        }
    }
}

extern "C" void kernel_launch(void* const* d_in, const int* in_sizes, int n_in,
                              void* d_out, int out_size, void* d_ws, size_t ws_size,
                              hipStream_t stream) {
    const float* x      = (const float*)d_in[0];
    const float* alphas = (const float*)d_in[1];
    const float* coeffs = (const float*)d_in[2];
    float* out = (float*)d_out;
    __bf16* w2 = (__bf16*)d_ws;   // 32768 bf16 = 64 KB

    build_w<<<16, 256, 0, stream>>>(alphas, coeffs, w2);
    darts_main<<<512, 256, 0, stream>>>(x, w2, out);
}

// Round 2
// 78.727 us; speedup vs baseline: 1.0175x; 1.0175x over previous
//
#include <hip/hip_runtime.h>
#include <hip/hip_bf16.h>
#include <stdint.h>

// out[b,j] = sum_{i,k} softmax(alphas[i,j,:])[k] * coeffs[i,j,k] * prim_k(x[b,i])
//         == P @ W2,  P[b, kg] = prim_op(x[b,i]),  W2[kg][j]
// with the k-ordering REMAPPED so the MFMA A-fragment needs one cacheline/lane:
//   kg = c*32 + quad*8 + j   <->   i = quad*16 + c , op = j     (c=0..15, quad=0..3)
// A-fragment (16x16x32: lane = m + 16*quad holds A[m][quad*8+j]):
//   lane (m,quad) supplies prim_j(x[row m][col quad*16 + c]) at step c
//   -> lane loads x[row][16q..16q+15] (one 64B line) into registers; prims in regs.
// B-fragment: W2 pre-swizzled by build_w so step-c/tile-t read is
//   wlds + c*2048 + t*512 + lane*8  -> contiguous 1KB/wave ds_read_b128, conflict-free.
// C/D layout: col=lane&15, row=quad*4+reg (m89-verified).
// No per-tile barriers: W2 staged once, one __syncthreads, then free-running.

typedef __bf16 bf16x8 __attribute__((ext_vector_type(8)));
typedef float f32x4 __attribute__((ext_vector_type(4)));

typedef __attribute__((address_space(1))) void gvoid;
typedef __attribute__((address_space(3))) void lvoid;

__device__ __forceinline__ void async16(const void* g, void* l) {
    // global -> LDS direct copy, 16 B/lane; LDS dest = wave-uniform base + lane*16
    __builtin_amdgcn_global_load_lds((gvoid*)g, (lvoid*)l, 16, 0, 0);
}

// ---------------- kernel 1: build W2 in MFMA B-fragment order (bf16) --------
__global__ void build_w(const float* __restrict__ alphas,
                        const float* __restrict__ coeffs,
                        __bf16* __restrict__ w2) {
    int gid = blockIdx.x * blockDim.x + threadIdx.x;   // 0..4095 == i*64 + n
    int i = gid >> 6;
    int n = gid & 63;
    const float* a = alphas + gid * 8;
    const float* c = coeffs + gid * 8;

    float av[8], mx = -1e30f;
#pragma unroll
    for (int k = 0; k < 8; ++k) { av[k] = a[k]; mx = fmaxf(mx, av[k]); }
    float e[8], s = 0.f;
#pragma unroll
    for (int k = 0; k < 8; ++k) { e[k] = __expf(av[k] - mx); s += e[k]; }
    float inv = 1.0f / s;

    bf16x8 w;
#pragma unroll
    for (int k = 0; k < 8; ++k) w[k] = (__bf16)(e[k] * inv * c[k]);

    // i = q*16 + cc (q = quad, cc = step); n = t*16 + nl
    int q = i >> 4, cc = i & 15, t = n >> 4, nl = n & 15;
    int pos = ((cc * 4 + t) * 64 + q * 16 + nl) * 8;
    *(bf16x8*)(w2 + pos) = w;    // 16B store
}

// ---------------- kernel 2: main GEMM -------------------------------------
// grid 512 x 512 threads (8 waves). LDS: W2 64KB only -> 2 blocks/CU, 16 waves/CU.
// Each block: one 128-row tile; each wave: 16 rows x 64 cols (64 MFMAs).
__global__ __launch_bounds__(512, 4) void darts_main(const float* __restrict__ x,
                                                     const __bf16* __restrict__ w2,
                                                     float* __restrict__ out) {
    __shared__ __bf16 wlds[32768];   // 64 KB, B-fragment order

    const int tid  = threadIdx.x;
    const int lane = tid & 63;
    const int wv   = tid >> 6;       // 0..7
    const int m    = lane & 15;      // A-row within 16-tile
    const int q    = lane >> 4;      // quad

    // x loads first (HBM-latency critical); one 64B line per lane, in registers
    const int row = blockIdx.x * 128 + wv * 16 + m;
    const float* xp = x + row * 64 + q * 16;
    f32x4 xr0 = *(const f32x4*)(xp + 0);
    f32x4 xr1 = *(const f32x4*)(xp + 4);
    f32x4 xr2 = *(const f32x4*)(xp + 8);
    f32x4 xr3 = *(const f32x4*)(xp + 12);

    // stage W2: straight 64KB copy (8 iters x 512 threads x 16B), W2 is L2-hot
#pragma unroll
    for (int it = 0; it < 8; ++it) {
        async16((const char*)w2 + (it * 512 + tid) * 16,
                (char*)wlds + it * 8192 + wv * 1024);
    }
    __syncthreads();   // drains vmcnt(0): W2 resident, x regs loaded

    float xa[16];
#pragma unroll
    for (int c = 0; c < 4; ++c) { xa[c] = xr0[c]; xa[4+c] = xr1[c]; xa[8+c] = xr2[c]; xa[12+c] = xr3[c]; }

    f32x4 acc0 = {0.f, 0.f, 0.f, 0.f};
    f32x4 acc1 = {0.f, 0.f, 0.f, 0.f};
    f32x4 acc2 = {0.f, 0.f, 0.f, 0.f};
    f32x4 acc3 = {0.f, 0.f, 0.f, 0.f};

#pragma unroll
    for (int c = 0; c < 16; ++c) {
        float xv = xa[c];
        float x2 = xv * xv;
        bf16x8 a;
        a[0] = (__bf16)0.0f;                      // 'none'
        a[1] = (__bf16)xv;                        // linear
        a[2] = (__bf16)x2;                        // x^2
        a[3] = (__bf16)(x2 * xv);                 // x^3
        a[4] = (__bf16)__expf(xv);                // exp
        a[5] = (__bf16)__logf(xv);                // ln
        a[6] = (__bf16)__builtin_amdgcn_rcpf(xv); // 1/x
        a[7] = (__bf16)__sinf(xv);                // sin

        const __bf16* bb = wlds + c * 2048 + lane * 8;
        bf16x8 b0 = *(const bf16x8*)(bb);
        bf16x8 b1 = *(const bf16x8*)(bb + 512);
        bf16x8 b2 = *(const bf16x8*)(bb + 1024);
        bf16x8 b3 = *(const bf16x8*)(bb + 1536);
        acc0 = __builtin_amdgcn_mfma_f32_16x16x32_bf16(a, b0, acc0, 0, 0, 0);
        acc1 = __builtin_amdgcn_mfma_f32_16x16x32_bf16(a, b1, acc1, 0, 0, 0);
        acc2 = __builtin_amdgcn_mfma_f32_16x16x32_bf16(a, b2, acc2, 0, 0, 0);
        acc3 = __builtin_amdgcn_mfma_f32_16x16x32_bf16(a, b3, acc3, 0, 0, 0);
    }

    // epilogue: C layout col=lane&15, row=q*4+r; 64B-segment-efficient dword stores
    float* orow = out + (blockIdx.x * 128 + wv * 16 + q * 4) * 64 + m;
#pragma unroll
    for (int r = 0; r < 4; ++r) {
        orow[r * 64 + 0]  = acc0[r];
        orow[r * 64 + 16] = acc1[r];
        orow[r * 64 + 32] = acc2[r];
        orow[r * 64 + 48] = acc3[r];
    }
}

extern "C" void kernel_launch(void* const* d_in, const int* in_sizes, int n_in,
                              void* d_out, int out_size, void* d_ws, size_t ws_size,
                              hipStream_t stream) {
    const float* x      = (const float*)d_in[0];
    const float* alphas = (const float*)d_in[1];
    const float* coeffs = (const float*)d_in[2];
    float* out = (float*)d_out;
    __bf16* w2 = (__bf16*)d_ws;   // 32768 bf16 = 64 KB

    build_w<<<16, 256, 0, stream>>>(alphas, coeffs, w2);
    darts_main<<<512, 512, 0, stream>>>(x, w2, out);
}